// Round 6
// baseline (512.449 us; speedup 1.0000x reference)
//
#include <hip/hip_runtime.h>
#include <stdint.h>

#define BATCH   32
#define GRID_HW 5776        // 76*76
#define NA      3
#define NPB     (NA*GRID_HW) // 17328 boxes per batch
#define NCLS    80
#define MAXDET  300
#define NBINS   4096
#define CANDN   512
#define T2      1024
#define CHUNK   17          // ceil(17328/1024)
#define NQ      (BATCH*NPB/4)   // 138624 quads
#define S4      (GRID_HW/4)     // 1444 float4 channel stride
#define NPB4    (NPB/4)         // 4332 float4 masks per batch
#define QPB     (NPB/4)         // quads per batch = 4332
#define NBLK    256             // fused grid: one block per CU
#define SLICE   542             // ceil(NQ/NBLK); 256*542 = 138752 >= 138624

__device__ __forceinline__ float sigf(float x){ return 1.0f/(1.0f + expf(-x)); }

__device__ __forceinline__ int binf(float v){
    if (v < 0.0f) return 0;
    int b = (int)(v * 4096.0f);
    return b > (NBINS-1) ? (NBINS-1) : b;
}

__device__ __forceinline__ unsigned int ordf(float v){
    unsigned int u = __float_as_uint(v);
    return (u & 0x80000000u) ? ~u : (u | 0x80000000u);
}

// -------- Phase 0: zero the per-batch completion counters --------
__global__ void zero_kernel(unsigned int* __restrict__ qdone)
{
    int i = threadIdx.x;
    if (i < BATCH) qdone[i] = 0u;
}

// -------- per-batch postproc: verbatim round-4 logic, parameterized by b --------
__device__ void postproc_batch(int b, int t,
                               const float* __restrict__ x,
                               const float* __restrict__ anchors,
                               const float* __restrict__ wmsk,
                               const int* __restrict__ wlab,
                               float* __restrict__ out,
                               unsigned int* shist, unsigned int* wsum,
                               unsigned long long* scan64, unsigned long long* cand,
                               float* sbx, float* sby, float* sbz, float* sbw2,
                               float* ssc, int* slab,
                               unsigned long long (*adj)[5], unsigned long long* kmask,
                               int* s_bin, int* s_cnt)
{
    int wid = t >> 6, lane = t & 63;
    const float* msk = wmsk + (size_t)b * NPB;
    const float4* msk4 = (const float4*)msk;           // 16B-aligned

    __syncthreads();                                    // guard shared reuse across calls

    // --- build per-batch histogram in LDS (float4 loads) ---
    for (int i = t; i < NBINS; i += T2) shist[i] = 0u;
    if (t == 0){ *s_bin = -2; *s_cnt = 0; }
    __syncthreads();
    for (int i4 = t; i4 < NPB4; i4 += T2){
        float4 v4 = msk4[i4];
        if (v4.x >= 0.0f) atomicAdd(&shist[binf(v4.x)], 1u);
        if (v4.y >= 0.0f) atomicAdd(&shist[binf(v4.y)], 1u);
        if (v4.z >= 0.0f) atomicAdd(&shist[binf(v4.z)], 1u);
        if (v4.w >= 0.0f) atomicAdd(&shist[binf(v4.w)], 1u);
    }
    __syncthreads();

    // --- 3-level scan over 4-bin chunk sums to find cutoff bin ---
    unsigned int cs = shist[4*t] + shist[4*t+1] + shist[4*t+2] + shist[4*t+3];
    unsigned int vI = cs;
    #pragma unroll
    for (int d = 1; d < 64; d <<= 1){
        unsigned int o = __shfl_up(vI, d);
        if (lane >= d) vI += o;
    }
    if (lane == 63) wsum[wid] = vI;
    __syncthreads();
    if (t < 16){
        unsigned int s = wsum[t];
        #pragma unroll
        for (int d = 1; d < 16; d <<= 1){
            unsigned int o = __shfl_up(s, d);
            if (t >= d) s += o;
        }
        wsum[t] = s;   // inclusive over waves
    }
    __syncthreads();
    unsigned int S = vI + (wid ? wsum[wid-1] : 0u);
    unsigned int total = wsum[15];
    if (total >= MAXDET){
        unsigned int c = total - S;
        #pragma unroll
        for (int k = 3; k >= 0; --k){
            unsigned int cg = c + shist[4*t + k];
            if (c < MAXDET && cg >= MAXDET) *s_bin = 4*t + k;
            c = cg;
        }
    }
    __syncthreads();
    int cb = *s_bin;

    // --- order-free compaction of all candidates with bin >= cb (float4) ---
    if (cb >= 0){
        for (int i4 = t; i4 < NPB4; i4 += T2){
            float4 v4 = msk4[i4];
            float vv[4] = {v4.x, v4.y, v4.z, v4.w};
            #pragma unroll
            for (int j = 0; j < 4; ++j){
                float v = vv[j];
                bool pred = (v >= 0.0f) && (binf(v) >= cb);
                unsigned long long bal = __ballot(pred);
                if (bal){
                    int cnt = __popcll(bal);
                    int leader = __ffsll((long long)bal) - 1;
                    int lbase = 0;
                    if (lane == leader) lbase = atomicAdd(s_cnt, cnt);
                    int base = __shfl(lbase, leader);
                    if (pred){
                        int off = __popcll(bal & ((1ull << lane) - 1ull));
                        int pos = base + off;
                        if (pos < CANDN){
                            int m = 4*i4 + j;
                            int aidx = m / GRID_HW;
                            int hw   = m - aidx * GRID_HW;
                            unsigned int n = (unsigned int)(hw * 3 + aidx);
                            cand[pos] = ((unsigned long long)ordf(v) << 32) | (~n);
                        }
                    }
                }
            }
        }
    }
    __syncthreads();
    int cnum = *s_cnt;
    bool exact = (cb >= 0) && (cnum <= CANDN);         // cb>=0 implies cnum >= 300

    if (exact){
        for (int i = cnum + t; i < CANDN; i += T2) cand[i] = 0ull;
        __syncthreads();
        // bitonic sort descending, 512 keys
        for (int k2 = 2; k2 <= CANDN; k2 <<= 1){
            for (int j = k2 >> 1; j > 0; j >>= 1){
                if (t < CANDN){
                    int ixj = t ^ j;
                    if (ixj > t){
                        unsigned long long a1 = cand[t], b1 = cand[ixj];
                        bool up = ((t & k2) == 0);
                        if ((a1 < b1) == up){ cand[t] = b1; cand[ixj] = a1; }
                    }
                }
                __syncthreads();
            }
        }
    } else {
        // exact fallback: 300-step iterative max extraction (degenerate/tie path)
        unsigned long long lk[CHUNK];
        int cstart = t * CHUNK;
        int ccnt = NPB - cstart; ccnt = ccnt < 0 ? 0 : (ccnt > CHUNK ? CHUNK : ccnt);
        for (int k = 0; k < CHUNK; ++k) lk[k] = 0ull;
        for (int k = 0; k < ccnt; ++k){
            int m = cstart + k;
            int aidx = m / GRID_HW;
            int hw   = m - aidx * GRID_HW;
            unsigned int n = (unsigned int)(hw * 3 + aidx);
            lk[k] = ((unsigned long long)ordf(msk[m]) << 32) | (~n);
        }
        for (int it = 0; it < MAXDET; ++it){
            unsigned long long lm = 0ull;
            for (int k = 0; k < CHUNK; ++k) lm = lk[k] > lm ? lk[k] : lm;
            scan64[t] = lm;
            __syncthreads();
            for (int s = T2 >> 1; s > 0; s >>= 1){
                if (t < s){ unsigned long long o = scan64[t+s]; if (o > scan64[t]) scan64[t] = o; }
                __syncthreads();
            }
            unsigned long long win = scan64[0];
            if (t == 0) cand[it] = win;
            for (int k = 0; k < CHUNK; ++k) if (lk[k] == win) lk[k] = 0ull;
            __syncthreads();
        }
        for (int i = MAXDET + t; i < CANDN; i += T2) cand[i] = 0ull;
        __syncthreads();
    }

    // --- selected 300: recompute boxes from x (bit-identical math) ---
    {
        bool valid = false;
        if (t < MAXDET){
            unsigned long long key = cand[t];
            unsigned int n = ~((unsigned int)key);
            int aidx = (int)(n % 3u);
            int hw   = (int)(n / 3u);
            int m    = aidx * GRID_HW + hw;
            float v  = msk[m];
            valid = v > -0.5f;

            int h = hw / 76;
            int w = hw - h * 76;
            const float* p = x + (size_t)(b * 255 + aidx * 85) * GRID_HW + hw;
            float tx = p[0];
            float ty = p[GRID_HW];
            float tw = p[2*GRID_HW];
            float th = p[3*GRID_HW];
            float aw = anchors[aidx*2], ah = anchors[aidx*2+1];

            float sx = 1.2f * sigf(tx) - 0.1f;
            float sy = 1.2f * sigf(ty) - 0.1f;
            float bxc = (sx + (float)w) / 76.0f;
            float byc = (sy + (float)h) / 76.0f;
            float bw = fminf(fmaxf(expf(tw)*aw, 0.0f), 2.0f);
            float bh = fminf(fmaxf(expf(th)*ah, 0.0f), 2.0f);
            float tlx = bxc - 0.5f*bw, tly = byc - 0.5f*bh;
            float brx = tlx + bw,      bry = tly + bh;

            sbx[t]  = fminf(fmaxf(tlx,0.0f),1.0f);
            sby[t]  = fminf(fmaxf(tly,0.0f),1.0f);
            sbz[t]  = fminf(fmaxf(brx,0.0f),1.0f);
            sbw2[t] = fminf(fmaxf(bry,0.0f),1.0f);
            ssc[t]  = valid ? v : 0.0f;
            slab[t] = wlab[(size_t)b * NPB + m];
        }
        if (wid < 5){
            unsigned long long bal = __ballot(valid);
            if (lane == 0) kmask[wid] = bal;
        }
    }
    __syncthreads();

    // --- adjacency via ballot: adj[i][w] bit j = iou(i, w*64+j) > 0.7, j > i ---
    for (int task = wid; task < MAXDET*5; task += 16){
        int i  = task / 5;
        int w2 = task - i * 5;
        int j  = w2 * 64 + lane;
        int jc = j < MAXDET ? j : (MAXDET-1);
        float lx = fmaxf(sbx[i], sbx[jc]);
        float ly = fmaxf(sby[i], sby[jc]);
        float rx = fminf(sbz[i], sbz[jc]);
        float ry = fminf(sbw2[i], sbw2[jc]);
        float iw = fmaxf(rx - lx, 0.0f);
        float ih = fmaxf(ry - ly, 0.0f);
        float inter = iw * ih;
        float a1 = (sbz[i]-sbx[i]) * (sbw2[i]-sby[i]);
        float a2 = (sbz[jc]-sbx[jc]) * (sbw2[jc]-sby[jc]);
        float iou = inter / (a1 + a2 - inter + 1e-9f);
        bool pred = (j < MAXDET) && (j > i) && (iou > 0.7f);
        unsigned long long bal = __ballot(pred);
        if (lane == 0) adj[i][w2] = bal;
    }
    __syncthreads();

    // --- exact sequential NMS: wave 0, keep-mask in registers, adj prefetched ---
    if (t < 64){
        unsigned long long km0 = kmask[0], km1 = kmask[1], km2 = kmask[2],
                           km3 = kmask[3], km4 = kmask[4];
        unsigned long long c0 = adj[0][0], c1 = adj[0][1], c2 = adj[0][2],
                           c3 = adj[0][3], c4 = adj[0][4];
        #define NMS_BLK(B, LIM, KM)                                            \
        for (int i2 = 0; i2 < (LIM); ++i2){                                    \
            int i = (B)*64 + i2;                                               \
            unsigned long long n0=0ull,n1=0ull,n2=0ull,n3=0ull,n4=0ull;        \
            if (i + 1 < MAXDET){                                               \
                n0 = adj[i+1][0]; n1 = adj[i+1][1]; n2 = adj[i+1][2];          \
                n3 = adj[i+1][3]; n4 = adj[i+1][4];                            \
            }                                                                  \
            unsigned long long m2 = ((KM >> i2) & 1ull) ? ~0ull : 0ull;        \
            km0 &= ~(c0 & m2);                                                 \
            km1 &= ~(c1 & m2);                                                 \
            km2 &= ~(c2 & m2);                                                 \
            km3 &= ~(c3 & m2);                                                 \
            km4 &= ~(c4 & m2);                                                 \
            c0 = n0; c1 = n1; c2 = n2; c3 = n3; c4 = n4;                       \
        }
        NMS_BLK(0, 64, km0)
        NMS_BLK(1, 64, km1)
        NMS_BLK(2, 64, km2)
        NMS_BLK(3, 64, km3)
        NMS_BLK(4, 44, km4)
        #undef NMS_BLK
        if (t == 0){
            kmask[0] = km0; kmask[1] = km1; kmask[2] = km2;
            kmask[3] = km3; kmask[4] = km4;
        }
    }
    __syncthreads();

    // --- outputs: boxes | scores | labels | keep (concatenated, f32) ---
    if (t < MAXDET){
        float* ob = out + (size_t)b * (MAXDET*4) + (size_t)t * 4;
        ob[0] = sbx[t]; ob[1] = sby[t]; ob[2] = sbz[t]; ob[3] = sbw2[t];
        out[BATCH*MAXDET*4 + b*MAXDET + t] = ssc[t];
        out[BATCH*MAXDET*5 + b*MAXDET + t] = (float)slab[t];
        out[BATCH*MAXDET*6 + b*MAXDET + t] = ((kmask[t >> 6] >> (t & 63)) & 1ull) ? 1.0f : 0.0f;
    }
}

// -------- Fused: decode window + last-block-per-batch postproc --------
__global__ __launch_bounds__(T2) void fused_kernel(const float* __restrict__ x,
                                                   const float* __restrict__ anchors,
                                                   float* __restrict__ wmsk,
                                                   int* __restrict__ wlab,
                                                   unsigned int* __restrict__ qdone,
                                                   float* __restrict__ out)
{
    __shared__ unsigned int shist[NBINS];              // 16 KB
    __shared__ unsigned int wsum[16];
    __shared__ unsigned long long scan64[T2];          // 8 KB (fallback only)
    __shared__ unsigned long long cand[CANDN];         // 4 KB
    __shared__ float sbx[MAXDET], sby[MAXDET], sbz[MAXDET], sbw2[MAXDET];
    __shared__ float ssc[MAXDET];
    __shared__ int   slab[MAXDET];
    __shared__ unsigned long long adj[MAXDET][5];      // 12 KB
    __shared__ unsigned long long kmask[5];
    __shared__ int s_bin, s_cnt;
    __shared__ int s_do[2];

    int t   = threadIdx.x;
    int blk = blockIdx.x;
    int q0  = blk * SLICE;
    int q1  = q0 + SLICE; if (q1 > NQ) q1 = NQ;

    // --- decode: one quad per thread (verbatim round-4 math) ---
    int q = q0 + t;
    if (q < q1){
        int b   = q / QPB;
        int r   = q - b * QPB;
        int a   = r / S4;
        int hw4 = r - a * S4;

        const float4* p4 = (const float4*)(x + (size_t)(b * 255 + a * 85) * GRID_HW) + hw4;

        float4 tov = p4[4*S4];

        float bx0=-1.0f, bx1=-1.0f, bx2=-1.0f, bx3=-1.0f;
        int   l0=0, l1=0, l2=0, l3=0;
        const float4* pc = p4 + 5*S4;
        #pragma unroll 4
        for (int c = 0; c < NCLS; ++c){
            float4 v = pc[(size_t)c * S4];
            float s;
            s = sigf(v.x); if (s > bx0){ bx0 = s; l0 = c; }
            s = sigf(v.y); if (s > bx1){ bx1 = s; l1 = c; }
            s = sigf(v.z); if (s > bx2){ bx2 = s; l2 = c; }
            s = sigf(v.w); if (s > bx3){ bx3 = s; l3 = c; }
        }

        float to[4]    = {tov.x, tov.y, tov.z, tov.w};
        float bestv[4] = {bx0, bx1, bx2, bx3};
        int   bestl[4] = {l0, l1, l2, l3};

        #pragma unroll
        for (int j = 0; j < 4; ++j){
            float obj = sigf(to[j]);
            float score = bestv[j] * obj;
            bool valid = (obj >= 0.5f) && (score >= 0.05f);

            int m = 4*q + j;
            wmsk[m] = valid ? score : -1.0f;
            wlab[m] = bestl[j];
        }
    }

    // --- release our writes, then count this window's quads per batch ---
    __threadfence();                                   // device-scope release
    __syncthreads();
    if (t == 0){
        s_do[0] = -1; s_do[1] = -1;
        int b0 = q0 / QPB;
        int b1 = (q1 - 1) / QPB;
        int e0 = (b0 + 1) * QPB; if (e0 > q1) e0 = q1;
        int c0 = e0 - q0;
        unsigned int o0 = atomicAdd(&qdone[b0], (unsigned int)c0);
        if ((int)o0 + c0 == QPB) s_do[0] = b0;
        if (b1 != b0){
            int c1 = q1 - b1 * QPB;
            unsigned int o1 = atomicAdd(&qdone[b1], (unsigned int)c1);
            if ((int)o1 + c1 == QPB) s_do[1] = b1;
        }
    }
    __syncthreads();
    if (s_do[0] < 0 && s_do[1] < 0) return;            // uniform exit

    __threadfence();                                   // device-scope acquire before reading others' wmsk/wlab

    if (s_do[0] >= 0)
        postproc_batch(s_do[0], t, x, anchors, wmsk, wlab, out,
                       shist, wsum, scan64, cand, sbx, sby, sbz, sbw2,
                       ssc, slab, adj, kmask, &s_bin, &s_cnt);
    if (s_do[1] >= 0)
        postproc_batch(s_do[1], t, x, anchors, wmsk, wlab, out,
                       shist, wsum, scan64, cand, sbx, sby, sbz, sbw2,
                       ssc, slab, adj, kmask, &s_bin, &s_cnt);
}

extern "C" void kernel_launch(void* const* d_in, const int* in_sizes, int n_in,
                              void* d_out, int out_size, void* d_ws, size_t ws_size,
                              hipStream_t stream)
{
    const float* x       = (const float*)d_in[0];
    const float* anchors = (const float*)d_in[1];
    float* out = (float*)d_out;

    char* ws = (char*)d_ws;
    float*        wmsk  = (float*)ws;                                   // 2,217,984 B
    int*          wlab  = (int*)  (ws + (size_t)BATCH*NPB*4);           // +2,217,984 B
    unsigned int* qdone = (unsigned int*)(ws + (size_t)BATCH*NPB*8);    // +128 B

    zero_kernel<<<1, 64, 0, stream>>>(qdone);
    fused_kernel<<<NBLK, T2, 0, stream>>>(x, anchors, wmsk, wlab, qdone, out);
}

// Round 7
// 344.504 us; speedup vs baseline: 1.4875x; 1.4875x over previous
//
#include <hip/hip_runtime.h>
#include <stdint.h>

#define BATCH   32
#define GRID_HW 5776        // 76*76
#define NA      3
#define NPB     (NA*GRID_HW) // 17328 boxes per batch
#define NCLS    80
#define MAXDET  300
#define NBINS   4096
#define CANDN   512
#define T2      1024
#define CHUNK   17          // ceil(17328/1024)
#define S4      (GRID_HW/4)     // 1444 float4 channel stride
#define NPB4    (NPB/4)         // 4332 float4 masks per batch

// streaming decode geometry
#define TPB_D   256             // 4 waves
#define TILE4   64              // float4 of one plane per block
#define NT      23              // tiles per plane: 22*64 + 36 = 1444
#define CPW     20              // class channels per wave (4*20 = 80)

__device__ __forceinline__ float sigf(float x){ return 1.0f/(1.0f + expf(-x)); }

__device__ __forceinline__ int binf(float v){
    if (v < 0.0f) return 0;
    int b = (int)(v * 4096.0f);
    return b > (NBINS-1) ? (NBINS-1) : b;
}

__device__ __forceinline__ unsigned int ordf(float v){
    unsigned int u = __float_as_uint(v);
    return (u & 0x80000000u) ? ~u : (u | 0x80000000u);
}

// -------- Phase 1: channel-parallel streaming decode --------
// Block = one (b, a, hw-tile of 256 boxes). Wave w owns 20 class channels and
// issues 20 INDEPENDENT coalesced 1KB loads (vs the old 80-deep per-thread
// chain at 27% occupancy). Per-lane argmax via packed u64 key:
//   key = bits(sigmoid(logit)) << 32 | (NCLS-1-c)
// sigmoid > 0 so float bits are order-monotone; ties resolve to smaller c —
// exactly np.argmax first-index semantics. Cross-wave max via 8KB LDS.
// wmsk/wlab outputs are bit-identical to the verified round-4 decode.
__global__ __launch_bounds__(TPB_D) void decode_kernel(const float* __restrict__ x,
                                                       float* __restrict__ wmsk,
                                                       int* __restrict__ wlab)
{
    __shared__ unsigned long long sk[4][4][TILE4];   // [elem j][wave][float4 idx] = 8 KB

    int blk  = blockIdx.x;
    int tile = blk % NT;
    int ba   = blk / NT;          // 0..95
    int a    = ba % NA;
    int b    = ba / NA;

    int t = threadIdx.x;
    int w = t >> 6, l = t & 63;

    int tf0 = tile * TILE4;                              // first float4 of tile in plane
    int tc  = S4 - tf0; if (tc > TILE4) tc = TILE4;      // 64 (or 36 on last tile)

    const float4* xp = (const float4*)x;
    size_t clsBase = (size_t)(b*255 + a*85 + 5) * S4;    // class-c plane at clsBase + c*S4

    if (l < tc){
        unsigned long long b0 = 0ull, b1 = 0ull, b2 = 0ull, b3 = 0ull;
        size_t p0 = clsBase + (size_t)(CPW*w) * S4 + (size_t)(tf0 + l);
        #pragma unroll
        for (int ci = 0; ci < CPW; ++ci){
            int c = CPW*w + ci;
            float4 v = xp[p0 + (size_t)ci * S4];
            unsigned long long lo = (unsigned long long)(unsigned)(NCLS-1-c);
            unsigned long long k;
            k = ((unsigned long long)__float_as_uint(sigf(v.x)) << 32) | lo;
            if (k > b0) b0 = k;
            k = ((unsigned long long)__float_as_uint(sigf(v.y)) << 32) | lo;
            if (k > b1) b1 = k;
            k = ((unsigned long long)__float_as_uint(sigf(v.z)) << 32) | lo;
            if (k > b2) b2 = k;
            k = ((unsigned long long)__float_as_uint(sigf(v.w)) << 32) | lo;
            if (k > b3) b3 = k;
        }
        sk[0][w][l] = b0;
        sk[1][w][l] = b1;
        sk[2][w][l] = b2;
        sk[3][w][l] = b3;
    }
    __syncthreads();

    // reduction: thread t handles local box t (hw = tf0*4 + t)
    if (t < 4*tc){
        int f4i = t >> 2, j = t & 3;
        unsigned long long k0 = sk[j][0][f4i], k1 = sk[j][1][f4i],
                           k2 = sk[j][2][f4i], k3 = sk[j][3][f4i];
        unsigned long long ka = k0 > k1 ? k0 : k1;
        unsigned long long kb = k2 > k3 ? k2 : k3;
        unsigned long long k  = ka > kb ? ka : kb;
        float s  = __uint_as_float((unsigned)(k >> 32));
        int lab  = (NCLS-1) - (int)(k & 0xFFFFFFFFull);

        int hw = tf0*4 + t;
        float objv = x[((size_t)(b*255 + a*85) + 4) * GRID_HW + hw];
        float obj  = sigf(objv);
        float score = s * obj;
        bool valid = (obj >= 0.5f) && (score >= 0.05f);

        int m = b*NPB + a*GRID_HW + hw;
        wmsk[m] = valid ? score : -1.0f;
        wlab[m] = lab;
    }
}

// -------- Phase 2+3: per-batch exact top-300 + NMS (verbatim round-4) --------
__global__ __launch_bounds__(T2) void postproc_kernel(const float* __restrict__ x,
                                                      const float* __restrict__ anchors,
                                                      const float* __restrict__ wmsk,
                                                      const int* __restrict__ wlab,
                                                      float* __restrict__ out)
{
    __shared__ unsigned int shist[NBINS];              // 16 KB
    __shared__ unsigned int wsum[16];
    __shared__ unsigned long long scan64[T2];          // fallback only
    __shared__ unsigned long long cand[CANDN];
    __shared__ float sbx[MAXDET], sby[MAXDET], sbz[MAXDET], sbw2[MAXDET];
    __shared__ float ssc[MAXDET];
    __shared__ int   slab[MAXDET];
    __shared__ unsigned long long adj[MAXDET][5];
    __shared__ unsigned long long kmask[5];
    __shared__ int s_bin, s_cnt;

    int t = threadIdx.x;
    int b = blockIdx.x;
    int wid = t >> 6, lane = t & 63;
    const float* msk = wmsk + (size_t)b * NPB;
    const float4* msk4 = (const float4*)msk;           // 16B-aligned

    // --- build per-batch histogram in LDS (float4 loads) ---
    for (int i = t; i < NBINS; i += T2) shist[i] = 0u;
    if (t == 0){ s_bin = -2; s_cnt = 0; }
    __syncthreads();
    for (int i4 = t; i4 < NPB4; i4 += T2){
        float4 v4 = msk4[i4];
        if (v4.x >= 0.0f) atomicAdd(&shist[binf(v4.x)], 1u);
        if (v4.y >= 0.0f) atomicAdd(&shist[binf(v4.y)], 1u);
        if (v4.z >= 0.0f) atomicAdd(&shist[binf(v4.z)], 1u);
        if (v4.w >= 0.0f) atomicAdd(&shist[binf(v4.w)], 1u);
    }
    __syncthreads();

    // --- 3-level scan over 4-bin chunk sums to find cutoff bin ---
    unsigned int cs = shist[4*t] + shist[4*t+1] + shist[4*t+2] + shist[4*t+3];
    unsigned int vI = cs;
    #pragma unroll
    for (int d = 1; d < 64; d <<= 1){
        unsigned int o = __shfl_up(vI, d);
        if (lane >= d) vI += o;
    }
    if (lane == 63) wsum[wid] = vI;
    __syncthreads();
    if (t < 16){
        unsigned int s = wsum[t];
        #pragma unroll
        for (int d = 1; d < 16; d <<= 1){
            unsigned int o = __shfl_up(s, d);
            if (t >= d) s += o;
        }
        wsum[t] = s;   // inclusive over waves
    }
    __syncthreads();
    unsigned int S = vI + (wid ? wsum[wid-1] : 0u);    // inclusive scan over all threads <= t
    unsigned int total = wsum[15];
    if (total >= MAXDET){
        unsigned int c = total - S;                    // items in bins > 4t+3
        #pragma unroll
        for (int k = 3; k >= 0; --k){
            unsigned int cg = c + shist[4*t + k];
            if (c < MAXDET && cg >= MAXDET) s_bin = 4*t + k;
            c = cg;
        }
    }
    __syncthreads();
    int cb = s_bin;

    // --- order-free compaction of all candidates with bin >= cb (float4) ---
    if (cb >= 0){
        for (int i4 = t; i4 < NPB4; i4 += T2){
            float4 v4 = msk4[i4];
            float vv[4] = {v4.x, v4.y, v4.z, v4.w};
            #pragma unroll
            for (int j = 0; j < 4; ++j){
                float v = vv[j];
                bool pred = (v >= 0.0f) && (binf(v) >= cb);
                unsigned long long bal = __ballot(pred);
                if (bal){
                    int cnt = __popcll(bal);
                    int leader = __ffsll((long long)bal) - 1;
                    int lbase = 0;
                    if (lane == leader) lbase = atomicAdd(&s_cnt, cnt);
                    int base = __shfl(lbase, leader);
                    if (pred){
                        int off = __popcll(bal & ((1ull << lane) - 1ull));
                        int pos = base + off;
                        if (pos < CANDN){
                            int m = 4*i4 + j;
                            int aidx = m / GRID_HW;
                            int hw   = m - aidx * GRID_HW;
                            unsigned int n = (unsigned int)(hw * 3 + aidx); // reference flat index
                            cand[pos] = ((unsigned long long)ordf(v) << 32) | (~n);
                        }
                    }
                }
            }
        }
    }
    __syncthreads();
    int cnum = s_cnt;
    bool exact = (cb >= 0) && (cnum <= CANDN);         // cb>=0 implies cnum >= 300

    if (exact){
        for (int i = cnum + t; i < CANDN; i += T2) cand[i] = 0ull;
        __syncthreads();
        // bitonic sort descending, 512 keys
        for (int k2 = 2; k2 <= CANDN; k2 <<= 1){
            for (int j = k2 >> 1; j > 0; j >>= 1){
                if (t < CANDN){
                    int ixj = t ^ j;
                    if (ixj > t){
                        unsigned long long a1 = cand[t], b1 = cand[ixj];
                        bool up = ((t & k2) == 0);
                        if ((a1 < b1) == up){ cand[t] = b1; cand[ixj] = a1; }
                    }
                }
                __syncthreads();
            }
        }
    } else {
        // exact fallback: 300-step iterative max extraction (degenerate/tie path)
        unsigned long long lk[CHUNK];
        int cstart = t * CHUNK;
        int ccnt = NPB - cstart; ccnt = ccnt < 0 ? 0 : (ccnt > CHUNK ? CHUNK : ccnt);
        for (int k = 0; k < CHUNK; ++k) lk[k] = 0ull;
        for (int k = 0; k < ccnt; ++k){
            int m = cstart + k;
            int aidx = m / GRID_HW;
            int hw   = m - aidx * GRID_HW;
            unsigned int n = (unsigned int)(hw * 3 + aidx);
            lk[k] = ((unsigned long long)ordf(msk[m]) << 32) | (~n);
        }
        for (int it = 0; it < MAXDET; ++it){
            unsigned long long lm = 0ull;
            for (int k = 0; k < CHUNK; ++k) lm = lk[k] > lm ? lk[k] : lm;
            scan64[t] = lm;
            __syncthreads();
            for (int s = T2 >> 1; s > 0; s >>= 1){
                if (t < s){ unsigned long long o = scan64[t+s]; if (o > scan64[t]) scan64[t] = o; }
                __syncthreads();
            }
            unsigned long long win = scan64[0];
            if (t == 0) cand[it] = win;
            for (int k = 0; k < CHUNK; ++k) if (lk[k] == win) lk[k] = 0ull;
            __syncthreads();
        }
        for (int i = MAXDET + t; i < CANDN; i += T2) cand[i] = 0ull;
        __syncthreads();
    }

    // --- selected 300: recompute boxes from x (bit-identical math), labels from wlab ---
    {
        bool valid = false;
        if (t < MAXDET){
            unsigned long long key = cand[t];
            unsigned int n = ~((unsigned int)key);
            int aidx = (int)(n % 3u);
            int hw   = (int)(n / 3u);
            int m    = aidx * GRID_HW + hw;
            float v  = msk[m];
            valid = v > -0.5f;

            int h = hw / 76;
            int w = hw - h * 76;
            const float* p = x + (size_t)(b * 255 + aidx * 85) * GRID_HW + hw;
            float tx = p[0];
            float ty = p[GRID_HW];
            float tw = p[2*GRID_HW];
            float th = p[3*GRID_HW];
            float aw = anchors[aidx*2], ah = anchors[aidx*2+1];

            float sx = 1.2f * sigf(tx) - 0.1f;
            float sy = 1.2f * sigf(ty) - 0.1f;
            float bxc = (sx + (float)w) / 76.0f;
            float byc = (sy + (float)h) / 76.0f;
            float bw = fminf(fmaxf(expf(tw)*aw, 0.0f), 2.0f);
            float bh = fminf(fmaxf(expf(th)*ah, 0.0f), 2.0f);
            float tlx = bxc - 0.5f*bw, tly = byc - 0.5f*bh;
            float brx = tlx + bw,      bry = tly + bh;

            sbx[t]  = fminf(fmaxf(tlx,0.0f),1.0f);
            sby[t]  = fminf(fmaxf(tly,0.0f),1.0f);
            sbz[t]  = fminf(fmaxf(brx,0.0f),1.0f);
            sbw2[t] = fminf(fmaxf(bry,0.0f),1.0f);
            ssc[t]  = valid ? v : 0.0f;
            slab[t] = wlab[(size_t)b * NPB + m];
        }
        if (wid < 5){
            unsigned long long bal = __ballot(valid);
            if (lane == 0) kmask[wid] = bal;
        }
    }
    __syncthreads();

    // --- adjacency via ballot: adj[i][w] bit j = iou(i, w*64+j) > 0.7, j > i ---
    for (int task = wid; task < MAXDET*5; task += 16){
        int i  = task / 5;
        int w2 = task - i * 5;
        int j  = w2 * 64 + lane;
        int jc = j < MAXDET ? j : (MAXDET-1);
        float lx = fmaxf(sbx[i], sbx[jc]);
        float ly = fmaxf(sby[i], sby[jc]);
        float rx = fminf(sbz[i], sbz[jc]);
        float ry = fminf(sbw2[i], sbw2[jc]);
        float iw = fmaxf(rx - lx, 0.0f);
        float ih = fmaxf(ry - ly, 0.0f);
        float inter = iw * ih;
        float a1 = (sbz[i]-sbx[i]) * (sbw2[i]-sby[i]);
        float a2 = (sbz[jc]-sbx[jc]) * (sbw2[jc]-sby[jc]);
        float iou = inter / (a1 + a2 - inter + 1e-9f);
        bool pred = (j < MAXDET) && (j > i) && (iou > 0.7f);
        unsigned long long bal = __ballot(pred);
        if (lane == 0) adj[i][w2] = bal;
    }
    __syncthreads();

    // --- exact sequential NMS: wave 0, keep-mask in registers, adj prefetched ---
    if (t < 64){
        unsigned long long km0 = kmask[0], km1 = kmask[1], km2 = kmask[2],
                           km3 = kmask[3], km4 = kmask[4];
        unsigned long long c0 = adj[0][0], c1 = adj[0][1], c2 = adj[0][2],
                           c3 = adj[0][3], c4 = adj[0][4];
        #define NMS_BLK(B, LIM, KM)                                            \
        for (int i2 = 0; i2 < (LIM); ++i2){                                    \
            int i = (B)*64 + i2;                                               \
            unsigned long long n0=0ull,n1=0ull,n2=0ull,n3=0ull,n4=0ull;        \
            if (i + 1 < MAXDET){                                               \
                n0 = adj[i+1][0]; n1 = adj[i+1][1]; n2 = adj[i+1][2];          \
                n3 = adj[i+1][3]; n4 = adj[i+1][4];                            \
            }                                                                  \
            unsigned long long m2 = ((KM >> i2) & 1ull) ? ~0ull : 0ull;        \
            km0 &= ~(c0 & m2);                                                 \
            km1 &= ~(c1 & m2);                                                 \
            km2 &= ~(c2 & m2);                                                 \
            km3 &= ~(c3 & m2);                                                 \
            km4 &= ~(c4 & m2);                                                 \
            c0 = n0; c1 = n1; c2 = n2; c3 = n3; c4 = n4;                       \
        }
        NMS_BLK(0, 64, km0)
        NMS_BLK(1, 64, km1)
        NMS_BLK(2, 64, km2)
        NMS_BLK(3, 64, km3)
        NMS_BLK(4, 44, km4)
        #undef NMS_BLK
        if (t == 0){
            kmask[0] = km0; kmask[1] = km1; kmask[2] = km2;
            kmask[3] = km3; kmask[4] = km4;
        }
    }
    __syncthreads();

    // --- outputs: boxes | scores | labels | keep (concatenated, f32) ---
    if (t < MAXDET){
        float* ob = out + (size_t)b * (MAXDET*4) + (size_t)t * 4;
        ob[0] = sbx[t]; ob[1] = sby[t]; ob[2] = sbz[t]; ob[3] = sbw2[t];
        out[BATCH*MAXDET*4 + b*MAXDET + t] = ssc[t];
        out[BATCH*MAXDET*5 + b*MAXDET + t] = (float)slab[t];
        out[BATCH*MAXDET*6 + b*MAXDET + t] = ((kmask[t >> 6] >> (t & 63)) & 1ull) ? 1.0f : 0.0f;
    }
}

extern "C" void kernel_launch(void* const* d_in, const int* in_sizes, int n_in,
                              void* d_out, int out_size, void* d_ws, size_t ws_size,
                              hipStream_t stream)
{
    const float* x       = (const float*)d_in[0];
    const float* anchors = (const float*)d_in[1];
    float* out = (float*)d_out;

    char* ws = (char*)d_ws;
    float* wmsk = (float*)ws;                          // 2,217,984 B
    int*   wlab = (int*)(ws + (size_t)BATCH*NPB*4);    // +2,217,984 B

    decode_kernel<<<BATCH*NA*NT, TPB_D, 0, stream>>>(x, wmsk, wlab);
    postproc_kernel<<<BATCH, T2, 0, stream>>>(x, anchors, wmsk, wlab, out);
}